// Round 2
// baseline (17458.563 us; speedup 1.0000x reference)
//
#include <hip/hip_runtime.h>
#include <cstddef>

#define D 128
#define H 8

__device__ __forceinline__ float4 f4_zero() { return make_float4(0.f, 0.f, 0.f, 0.f); }

// ---------------------------------------------------------------------------
// C[M,128] = A[M,128] @ W[128,128]
// LN_EP=1: out = LN(resid + C + bias) * gamma + beta
// ZDIV=1:  A row m is scaled per-head by 1/(z[m,h]+1e-6)  (h_attn = wV/z)
// block: 256 threads, 64 rows per block. A tile staged in LDS, W streamed
// through L2 (every block reads the same 64KB).
// NOTE (LN_EP path): A == out aliasing is safe — each block fully stages its
// 64 A-rows into LDS before writing those same rows of out.
// ---------------------------------------------------------------------------
template <int LN_EP, int ZDIV>
__global__ __launch_bounds__(256) void gemm128_kernel(
    const float* __restrict__ A, const float* __restrict__ W,
    const float* __restrict__ bias, const float* __restrict__ resid,
    const float* __restrict__ gamma, const float* __restrict__ beta,
    const float* __restrict__ zarr, float* __restrict__ out, int M)
{
    __shared__ float as[64][132];
    __shared__ float s_mu[64], s_rs[64];

    const int tid = threadIdx.x;
    const int m0 = blockIdx.x * 64;

    // ---- stage A tile (64x128) ----
    for (int i = tid; i < 2048; i += 256) {
        const int r = i >> 5, c4 = i & 31;
        const int gr = m0 + r;
        float4 v = f4_zero();
        if (gr < M) {
            v = reinterpret_cast<const float4*>(A + (size_t)gr * D)[c4];
            if (ZDIV) {
                const float rz = 1.0f / (zarr[(size_t)gr * H + (c4 >> 2)] + 1e-6f);
                v.x *= rz; v.y *= rz; v.z *= rz; v.w *= rz;
            }
        }
        *reinterpret_cast<float4*>(&as[r][c4 << 2]) = v;
    }
    __syncthreads();

    const int tx = tid & 31;   // cols tx*4 .. tx*4+3
    const int ty = tid >> 5;   // rows ty*8 .. ty*8+7

    float acc[8][4];
#pragma unroll
    for (int r = 0; r < 8; ++r) { acc[r][0] = 0.f; acc[r][1] = 0.f; acc[r][2] = 0.f; acc[r][3] = 0.f; }

    const float* Wp = W + (tx << 2);
    for (int k = 0; k < 128; k += 4) {
        const float4 wv0 = *reinterpret_cast<const float4*>(Wp + (size_t)(k + 0) * D);
        const float4 wv1 = *reinterpret_cast<const float4*>(Wp + (size_t)(k + 1) * D);
        const float4 wv2 = *reinterpret_cast<const float4*>(Wp + (size_t)(k + 2) * D);
        const float4 wv3 = *reinterpret_cast<const float4*>(Wp + (size_t)(k + 3) * D);
        float4 av[8];
#pragma unroll
        for (int r = 0; r < 8; ++r)
            av[r] = *reinterpret_cast<const float4*>(&as[(ty << 3) + r][k]);
#pragma unroll
        for (int kk = 0; kk < 4; ++kk) {
            const float4 wv = (kk == 0) ? wv0 : (kk == 1) ? wv1 : (kk == 2) ? wv2 : wv3;
#pragma unroll
            for (int r = 0; r < 8; ++r) {
                const float a = (kk == 0) ? av[r].x : (kk == 1) ? av[r].y : (kk == 2) ? av[r].z : av[r].w;
                acc[r][0] = fmaf(a, wv.x, acc[r][0]);
                acc[r][1] = fmaf(a, wv.y, acc[r][1]);
                acc[r][2] = fmaf(a, wv.z, acc[r][2]);
                acc[r][3] = fmaf(a, wv.w, acc[r][3]);
            }
        }
    }

    if (!LN_EP) {
#pragma unroll
        for (int r = 0; r < 8; ++r) {
            const int gr = m0 + (ty << 3) + r;
            if (gr < M) {
                const float4 v = make_float4(acc[r][0], acc[r][1], acc[r][2], acc[r][3]);
                *reinterpret_cast<float4*>(out + (size_t)gr * D + (tx << 2)) = v;
            }
        }
    } else {
        __syncthreads();  // everyone done reading as[] before we overwrite it
        const float4 bi = *reinterpret_cast<const float4*>(bias + (tx << 2));
#pragma unroll
        for (int r = 0; r < 8; ++r) {
            const int lr = (ty << 3) + r, gr = m0 + lr;
            const float4 rv = (gr < M)
                ? *reinterpret_cast<const float4*>(resid + (size_t)gr * D + (tx << 2))
                : f4_zero();
            float4 y;
            y.x = acc[r][0] + bi.x + rv.x;
            y.y = acc[r][1] + bi.y + rv.y;
            y.z = acc[r][2] + bi.z + rv.z;
            y.w = acc[r][3] + bi.w + rv.w;
            *reinterpret_cast<float4*>(&as[lr][tx << 2]) = y;
        }
        __syncthreads();
        // row stats: 4 threads per row, 32 cols each
        {
            const int row = tid >> 2, part = tid & 3;
            float s = 0.f, q = 0.f;
            const int c0 = part << 5;
#pragma unroll
            for (int c = 0; c < 32; ++c) { const float v = as[row][c0 + c]; s += v; q = fmaf(v, v, q); }
            s += __shfl_xor(s, 1); q += __shfl_xor(q, 1);
            s += __shfl_xor(s, 2); q += __shfl_xor(q, 2);
            if (part == 0) {
                const float mu = s * (1.f / 128.f);
                const float var = q * (1.f / 128.f) - mu * mu;
                s_mu[row] = mu;
                s_rs[row] = rsqrtf(var + 1e-5f);
            }
        }
        __syncthreads();
        for (int i = tid; i < 2048; i += 256) {
            const int r = i >> 5, c4 = i & 31;
            const int gr = m0 + r;
            if (gr < M) {
                const float4 v = *reinterpret_cast<float4*>(&as[r][c4 << 2]);
                const float4 g = reinterpret_cast<const float4*>(gamma)[c4];
                const float4 b = reinterpret_cast<const float4*>(beta)[c4];
                const float mu = s_mu[r], rs = s_rs[r];
                float4 o;
                o.x = (v.x - mu) * rs * g.x + b.x;
                o.y = (v.y - mu) * rs * g.y + b.y;
                o.z = (v.z - mu) * rs * g.z + b.z;
                o.w = (v.w - mu) * rs * g.w + b.w;
                *reinterpret_cast<float4*>(out + (size_t)gr * D + (c4 << 2)) = o;
            }
        }
    }
}

// ---------------------------------------------------------------------------
// Fused FFN + residual + LN, in-place capable (row-disjoint blocks):
// out = LN(x + relu(x@W1 + b1) @ W2 + b2)
// block: 256 threads, 32 rows; hidden [32,256] lives in LDS only.
// ---------------------------------------------------------------------------
__global__ __launch_bounds__(256) void ffn_ln_kernel(
    const float* __restrict__ X,
    const float* __restrict__ W1, const float* __restrict__ b1,
    const float* __restrict__ W2, const float* __restrict__ b2,
    const float* __restrict__ gamma, const float* __restrict__ beta,
    float* __restrict__ out, int M)
{
    __shared__ float xs[32][132];
    __shared__ float hs[32][260];
    __shared__ float s_mu[32], s_rs[32];

    const int tid = threadIdx.x;
    const int m0 = blockIdx.x * 32;

    // stage x (32x128)
    for (int i = tid; i < 1024; i += 256) {
        const int r = i >> 5, c4 = i & 31;
        const int gr = m0 + r;
        const float4 v = (gr < M)
            ? reinterpret_cast<const float4*>(X + (size_t)gr * D)[c4]
            : f4_zero();
        *reinterpret_cast<float4*>(&xs[r][c4 << 2]) = v;
    }
    __syncthreads();

    // phase 1: hidden = relu(x @ W1 + b1)   (32 x 256)
    {
        const int tx = tid & 63;   // cols tx*4 (256 cols)
        const int ty = tid >> 6;   // rows ty*8..+7
        float acc[8][4];
#pragma unroll
        for (int r = 0; r < 8; ++r) { acc[r][0] = 0.f; acc[r][1] = 0.f; acc[r][2] = 0.f; acc[r][3] = 0.f; }
        const float* W1p = W1 + (tx << 2);
        for (int k = 0; k < 128; k += 4) {
            const float4 wv0 = *reinterpret_cast<const float4*>(W1p + (size_t)(k + 0) * 256);
            const float4 wv1 = *reinterpret_cast<const float4*>(W1p + (size_t)(k + 1) * 256);
            const float4 wv2 = *reinterpret_cast<const float4*>(W1p + (size_t)(k + 2) * 256);
            const float4 wv3 = *reinterpret_cast<const float4*>(W1p + (size_t)(k + 3) * 256);
            float4 av[8];
#pragma unroll
            for (int r = 0; r < 8; ++r)
                av[r] = *reinterpret_cast<const float4*>(&xs[(ty << 3) + r][k]);
#pragma unroll
            for (int kk = 0; kk < 4; ++kk) {
                const float4 wv = (kk == 0) ? wv0 : (kk == 1) ? wv1 : (kk == 2) ? wv2 : wv3;
#pragma unroll
                for (int r = 0; r < 8; ++r) {
                    const float a = (kk == 0) ? av[r].x : (kk == 1) ? av[r].y : (kk == 2) ? av[r].z : av[r].w;
                    acc[r][0] = fmaf(a, wv.x, acc[r][0]);
                    acc[r][1] = fmaf(a, wv.y, acc[r][1]);
                    acc[r][2] = fmaf(a, wv.z, acc[r][2]);
                    acc[r][3] = fmaf(a, wv.w, acc[r][3]);
                }
            }
        }
        const float4 bb = *reinterpret_cast<const float4*>(b1 + (tx << 2));
#pragma unroll
        for (int r = 0; r < 8; ++r) {
            float4 hv;
            hv.x = fmaxf(acc[r][0] + bb.x, 0.f);
            hv.y = fmaxf(acc[r][1] + bb.y, 0.f);
            hv.z = fmaxf(acc[r][2] + bb.z, 0.f);
            hv.w = fmaxf(acc[r][3] + bb.w, 0.f);
            *reinterpret_cast<float4*>(&hs[(ty << 3) + r][tx << 2]) = hv;
        }
    }
    __syncthreads();

    // phase 2: y = hidden @ W2 + b2 + x  -> overwrite xs (owner-only, no race)
    {
        const int tx = tid & 31;   // cols tx*4 (128 cols)
        const int ty = tid >> 5;   // rows ty*4..+3
        float acc[4][4];
#pragma unroll
        for (int r = 0; r < 4; ++r) { acc[r][0] = 0.f; acc[r][1] = 0.f; acc[r][2] = 0.f; acc[r][3] = 0.f; }
        const float* W2p = W2 + (tx << 2);
        for (int k = 0; k < 256; k += 4) {
            const float4 wv0 = *reinterpret_cast<const float4*>(W2p + (size_t)(k + 0) * D);
            const float4 wv1 = *reinterpret_cast<const float4*>(W2p + (size_t)(k + 1) * D);
            const float4 wv2 = *reinterpret_cast<const float4*>(W2p + (size_t)(k + 2) * D);
            const float4 wv3 = *reinterpret_cast<const float4*>(W2p + (size_t)(k + 3) * D);
            float4 av[4];
#pragma unroll
            for (int r = 0; r < 4; ++r)
                av[r] = *reinterpret_cast<const float4*>(&hs[(ty << 2) + r][k]);
#pragma unroll
            for (int kk = 0; kk < 4; ++kk) {
                const float4 wv = (kk == 0) ? wv0 : (kk == 1) ? wv1 : (kk == 2) ? wv2 : wv3;
#pragma unroll
                for (int r = 0; r < 4; ++r) {
                    const float a = (kk == 0) ? av[r].x : (kk == 1) ? av[r].y : (kk == 2) ? av[r].z : av[r].w;
                    acc[r][0] = fmaf(a, wv.x, acc[r][0]);
                    acc[r][1] = fmaf(a, wv.y, acc[r][1]);
                    acc[r][2] = fmaf(a, wv.z, acc[r][2]);
                    acc[r][3] = fmaf(a, wv.w, acc[r][3]);
                }
            }
        }
        const float4 bb = *reinterpret_cast<const float4*>(b2 + (tx << 2));
#pragma unroll
        for (int r = 0; r < 4; ++r) {
            const int lr = (ty << 2) + r;
            float4 y = *reinterpret_cast<float4*>(&xs[lr][tx << 2]);  // residual
            y.x += acc[r][0] + bb.x;
            y.y += acc[r][1] + bb.y;
            y.z += acc[r][2] + bb.z;
            y.w += acc[r][3] + bb.w;
            *reinterpret_cast<float4*>(&xs[lr][tx << 2]) = y;
        }
    }
    __syncthreads();

    // LN: 8 threads per row, 16 cols each
    {
        const int row = tid >> 3, part = tid & 7;
        float s = 0.f, q = 0.f;
        const int c0 = part << 4;
#pragma unroll
        for (int c = 0; c < 16; ++c) { const float v = xs[row][c0 + c]; s += v; q = fmaf(v, v, q); }
        s += __shfl_xor(s, 1); q += __shfl_xor(q, 1);
        s += __shfl_xor(s, 2); q += __shfl_xor(q, 2);
        s += __shfl_xor(s, 4); q += __shfl_xor(q, 4);
        if (part == 0) {
            const float mu = s * (1.f / 128.f);
            const float var = q * (1.f / 128.f) - mu * mu;
            s_mu[row] = mu;
            s_rs[row] = rsqrtf(var + 1e-5f);
        }
    }
    __syncthreads();

    for (int i = tid; i < 1024; i += 256) {
        const int r = i >> 5, c4 = i & 31;
        const int gr = m0 + r;
        if (gr < M) {
            const float4 v = *reinterpret_cast<float4*>(&xs[r][c4 << 2]);
            const float4 g = reinterpret_cast<const float4*>(gamma)[c4];
            const float4 b = reinterpret_cast<const float4*>(beta)[c4];
            const float mu = s_mu[r], rs = s_rs[r];
            float4 o;
            o.x = (v.x - mu) * rs * g.x + b.x;
            o.y = (v.y - mu) * rs * g.y + b.y;
            o.z = (v.z - mu) * rs * g.z + b.z;
            o.w = (v.w - mu) * rs * g.w + b.w;
            *reinterpret_cast<float4*>(out + (size_t)gr * D + (c4 << 2)) = o;
        }
    }
}

// ---------------------------------------------------------------------------
// Edge kernel: one edge per 32-lane group (8 edges / 256-thread block).
//   score[h] = dot(K[src],Q[dst])/4 ; e1 = score*pe (in-place over pe);
//   sc[h] = exp(clip(sum_dh e1, -5, 5));
//   atomic scatter: wV[dst] += V[src]*sc ; z[dst,h] += sc
// ---------------------------------------------------------------------------
__global__ __launch_bounds__(256) void edge_kernel(
    const float* __restrict__ Q, const float* __restrict__ K, const float* __restrict__ V,
    const int* __restrict__ src, const int* __restrict__ dst,
    float* __restrict__ pe_e1, float* __restrict__ wV, float* __restrict__ z, int E)
{
    const int tid = threadIdx.x;
    const int slot = tid >> 5, l = tid & 31;
    const long long e = (long long)blockIdx.x * 8 + slot;
    if (e >= E) return;

    const int s = src[e], d = dst[e];
    const int head = l >> 2;

    const float4 kv = reinterpret_cast<const float4*>(K + (size_t)s * D)[l];
    const float4 qv = reinterpret_cast<const float4*>(Q + (size_t)d * D)[l];
    float dot = kv.x * qv.x + kv.y * qv.y + kv.z * qv.z + kv.w * qv.w;
    dot += __shfl_xor(dot, 1);
    dot += __shfl_xor(dot, 2);
    const float score = dot * 0.25f;  // 1/sqrt(16)

    const float4 pe4 = reinterpret_cast<const float4*>(pe_e1 + (size_t)e * D)[l];
    float4 e1;
    e1.x = score * pe4.x; e1.y = score * pe4.y; e1.z = score * pe4.z; e1.w = score * pe4.w;
    reinterpret_cast<float4*>(pe_e1 + (size_t)e * D)[l] = e1;

    float ss = e1.x + e1.y + e1.z + e1.w;
    ss += __shfl_xor(ss, 1);
    ss += __shfl_xor(ss, 2);
    const float sc = expf(fminf(fmaxf(ss, -5.f), 5.f));

    const float4 vv = reinterpret_cast<const float4*>(V + (size_t)s * D)[l];
    float* wrow = wV + (size_t)d * D + (l << 2);
    atomicAdd(wrow + 0, vv.x * sc);
    atomicAdd(wrow + 1, vv.y * sc);
    atomicAdd(wrow + 2, vv.z * sc);
    atomicAdd(wrow + 3, vv.w * sc);
    if ((l & 3) == 0) atomicAdd(z + (size_t)d * H + head, sc);
}

// ---------------------------------------------------------------------------
extern "C" void kernel_launch(void* const* d_in, const int* in_sizes, int n_in,
                              void* d_out, int out_size, void* d_ws, size_t ws_size,
                              hipStream_t stream)
{
    const float* h    = (const float*)d_in[0];
    const float* e    = (const float*)d_in[1];
    const int*   src  = (const int*)d_in[2];
    const int*   dst  = (const int*)d_in[3];
    const float* Wq   = (const float*)d_in[4];
    const float* Wk   = (const float*)d_in[5];
    const float* Wv   = (const float*)d_in[6];
    const float* Wpe  = (const float*)d_in[7];
    const float* Oh_w = (const float*)d_in[8];
    const float* Oh_b = (const float*)d_in[9];
    const float* Oe_w = (const float*)d_in[10];
    const float* Oe_b = (const float*)d_in[11];
    const float* g1h  = (const float*)d_in[12];
    const float* b1h  = (const float*)d_in[13];
    const float* g1e  = (const float*)d_in[14];
    const float* b1e  = (const float*)d_in[15];
    const float* F1h_w = (const float*)d_in[16];
    const float* F1h_b = (const float*)d_in[17];
    const float* F2h_w = (const float*)d_in[18];
    const float* F2h_b = (const float*)d_in[19];
    const float* F1e_w = (const float*)d_in[20];
    const float* F1e_b = (const float*)d_in[21];
    const float* F2e_w = (const float*)d_in[22];
    const float* F2e_b = (const float*)d_in[23];
    const float* g2h  = (const float*)d_in[24];
    const float* b2h  = (const float*)d_in[25];
    const float* g2e  = (const float*)d_in[26];
    const float* b2e  = (const float*)d_in[27];

    const int N = in_sizes[0] / D;
    const int E = in_sizes[1] / D;

    // workspace layout (floats): Q | K | V | wV | z      (~104 MB for N=50k)
    // pe/e1 (E*D = 409.6 MB) lives in d_out's ee region — written fully by the
    // pe GEMM before anything reads it; all later consumers are row-in-place safe.
    float* ws   = (float*)d_ws;
    float* Qb   = ws;
    float* Kb   = Qb + (size_t)N * D;
    float* Vb   = Kb + (size_t)N * D;
    float* wVb  = Vb + (size_t)N * D;
    float* zb   = wVb + (size_t)N * D;

    float* hh = (float*)d_out;                    // N*D
    float* ee = (float*)d_out + (size_t)N * D;    // E*D
    float* peb = ee;                              // pe -> e1 -> ee (in place)

    // zero the scatter accumulators (wV and z are adjacent)
    hipMemsetAsync(wVb, 0, ((size_t)N * D + (size_t)N * H) * sizeof(float), stream);

    const dim3 blk(256);
    const int gn = (N + 63) / 64;
    const int ge = (E + 63) / 64;

    gemm128_kernel<0, 0><<<gn, blk, 0, stream>>>(h, Wq, nullptr, nullptr, nullptr, nullptr, nullptr, Qb, N);
    gemm128_kernel<0, 0><<<gn, blk, 0, stream>>>(h, Wk, nullptr, nullptr, nullptr, nullptr, nullptr, Kb, N);
    gemm128_kernel<0, 0><<<gn, blk, 0, stream>>>(h, Wv, nullptr, nullptr, nullptr, nullptr, nullptr, Vb, N);
    gemm128_kernel<0, 0><<<ge, blk, 0, stream>>>(e, Wpe, nullptr, nullptr, nullptr, nullptr, nullptr, peb, E);

    edge_kernel<<<(E + 7) / 8, blk, 0, stream>>>(Qb, Kb, Vb, src, dst, peb, wVb, zb, E);

    // hh1 = LN(h + (wV/z)@Oh_w + Oh_b)
    gemm128_kernel<1, 1><<<gn, blk, 0, stream>>>(wVb, Oh_w, Oh_b, h, g1h, b1h, zb, hh, N);
    // ee1 = LN(e + e1@Oe_w + Oe_b)   (A == out, row-in-place safe)
    gemm128_kernel<1, 0><<<ge, blk, 0, stream>>>(peb, Oe_w, Oe_b, e, g1e, b1e, nullptr, ee, E);

    // FFN + LN, in-place on d_out regions
    ffn_ln_kernel<<<(N + 31) / 32, blk, 0, stream>>>(hh, F1h_w, F1h_b, F2h_w, F2h_b, g2h, b2h, hh, N);
    ffn_ln_kernel<<<(E + 31) / 32, blk, 0, stream>>>(ee, F1e_w, F1e_b, F2e_w, F2e_b, g2e, b2e, ee, E);
}

// Round 4
// 4666.840 us; speedup vs baseline: 3.7410x; 3.7410x over previous
//
#include <hip/hip_runtime.h>
#include <cstddef>

#define D 128
#define H 8

__device__ __forceinline__ float4 f4_zero() { return make_float4(0.f, 0.f, 0.f, 0.f); }

// ---------------------------------------------------------------------------
// C[M,128] = A[M,128] @ W[128,128]
// LN_EP=1: out = LN(resid + C + bias) * gamma + beta
// ZDIV=1:  A row m is scaled per-head by 1/(z[m,h]+1e-6)  (h_attn = wV/z)
// block: 256 threads, 64 rows. A tile in LDS; W streamed from L2.
// REG BUDGET: acc 32 + wv 16 + av 4 + addr ~15 => ~70 VGPR. k-loop is
// `#pragma unroll 1` — round-2 profile showed the compiler's unroll/pipeline
// pushed this to 256 VGPR + scratch spill (29.5 GB HBM traffic, VALUBusy 3%).
// launch_bounds(256,4) caps at 128 VGPR / 4 waves per SIMD.
// NOTE (LN_EP path): A == out aliasing is safe — each block fully stages its
// 64 A-rows into LDS before writing those same rows of out.
// ---------------------------------------------------------------------------
template <int LN_EP, int ZDIV>
__global__ __launch_bounds__(256, 4) void gemm128_kernel(
    const float* __restrict__ A, const float* __restrict__ W,
    const float* __restrict__ bias, const float* __restrict__ resid,
    const float* __restrict__ gamma, const float* __restrict__ beta,
    const float* __restrict__ zarr, float* __restrict__ out, int M)
{
    __shared__ float as[64][132];
    __shared__ float s_mu[64], s_rs[64];

    const int tid = threadIdx.x;
    const int m0 = blockIdx.x * 64;

    // ---- stage A tile (64x128) ----
    for (int i = tid; i < 2048; i += 256) {
        const int r = i >> 5, c4 = i & 31;
        const int gr = m0 + r;
        float4 v = f4_zero();
        if (gr < M) {
            v = reinterpret_cast<const float4*>(A + (size_t)gr * D)[c4];
            if (ZDIV) {
                const float rz = 1.0f / (zarr[(size_t)gr * H + (c4 >> 2)] + 1e-6f);
                v.x *= rz; v.y *= rz; v.z *= rz; v.w *= rz;
            }
        }
        *reinterpret_cast<float4*>(&as[r][c4 << 2]) = v;
    }
    __syncthreads();

    const int tx = tid & 31;   // cols tx*4 .. tx*4+3
    const int ty = tid >> 5;   // rows ty*8 .. ty*8+7

    float acc[8][4];
#pragma unroll
    for (int r = 0; r < 8; ++r) { acc[r][0] = 0.f; acc[r][1] = 0.f; acc[r][2] = 0.f; acc[r][3] = 0.f; }

    const float* Wp = W + (tx << 2);
#pragma unroll 1
    for (int k = 0; k < 128; k += 4) {
        const float4 wv0 = *reinterpret_cast<const float4*>(Wp);
        const float4 wv1 = *reinterpret_cast<const float4*>(Wp + D);
        const float4 wv2 = *reinterpret_cast<const float4*>(Wp + 2 * D);
        const float4 wv3 = *reinterpret_cast<const float4*>(Wp + 3 * D);
        Wp += 4 * D;
#pragma unroll
        for (int r = 0; r < 8; ++r) {
            const float4 av = *reinterpret_cast<const float4*>(&as[(ty << 3) + r][k]);
            acc[r][0] = fmaf(av.x, wv0.x, acc[r][0]);
            acc[r][1] = fmaf(av.x, wv0.y, acc[r][1]);
            acc[r][2] = fmaf(av.x, wv0.z, acc[r][2]);
            acc[r][3] = fmaf(av.x, wv0.w, acc[r][3]);
            acc[r][0] = fmaf(av.y, wv1.x, acc[r][0]);
            acc[r][1] = fmaf(av.y, wv1.y, acc[r][1]);
            acc[r][2] = fmaf(av.y, wv1.z, acc[r][2]);
            acc[r][3] = fmaf(av.y, wv1.w, acc[r][3]);
            acc[r][0] = fmaf(av.z, wv2.x, acc[r][0]);
            acc[r][1] = fmaf(av.z, wv2.y, acc[r][1]);
            acc[r][2] = fmaf(av.z, wv2.z, acc[r][2]);
            acc[r][3] = fmaf(av.z, wv2.w, acc[r][3]);
            acc[r][0] = fmaf(av.w, wv3.x, acc[r][0]);
            acc[r][1] = fmaf(av.w, wv3.y, acc[r][1]);
            acc[r][2] = fmaf(av.w, wv3.z, acc[r][2]);
            acc[r][3] = fmaf(av.w, wv3.w, acc[r][3]);
        }
    }

    if (!LN_EP) {
#pragma unroll
        for (int r = 0; r < 8; ++r) {
            const int gr = m0 + (ty << 3) + r;
            if (gr < M) {
                const float4 v = make_float4(acc[r][0], acc[r][1], acc[r][2], acc[r][3]);
                *reinterpret_cast<float4*>(out + (size_t)gr * D + (tx << 2)) = v;
            }
        }
    } else {
        __syncthreads();  // everyone done reading as[] before we overwrite it
        const float4 bi = *reinterpret_cast<const float4*>(bias + (tx << 2));
#pragma unroll
        for (int r = 0; r < 8; ++r) {
            const int lr = (ty << 3) + r, gr = m0 + lr;
            const float4 rv = (gr < M)
                ? *reinterpret_cast<const float4*>(resid + (size_t)gr * D + (tx << 2))
                : f4_zero();
            float4 y;
            y.x = acc[r][0] + bi.x + rv.x;
            y.y = acc[r][1] + bi.y + rv.y;
            y.z = acc[r][2] + bi.z + rv.z;
            y.w = acc[r][3] + bi.w + rv.w;
            *reinterpret_cast<float4*>(&as[lr][tx << 2]) = y;
        }
        __syncthreads();
        // row stats: 4 threads per row, 32 cols each
        {
            const int row = tid >> 2, part = tid & 3;
            float s = 0.f, q = 0.f;
            const int c0 = part << 5;
#pragma unroll
            for (int c = 0; c < 32; ++c) { const float v = as[row][c0 + c]; s += v; q = fmaf(v, v, q); }
            s += __shfl_xor(s, 1); q += __shfl_xor(q, 1);
            s += __shfl_xor(s, 2); q += __shfl_xor(q, 2);
            if (part == 0) {
                const float mu = s * (1.f / 128.f);
                const float var = q * (1.f / 128.f) - mu * mu;
                s_mu[row] = mu;
                s_rs[row] = rsqrtf(var + 1e-5f);
            }
        }
        __syncthreads();
        for (int i = tid; i < 2048; i += 256) {
            const int r = i >> 5, c4 = i & 31;
            const int gr = m0 + r;
            if (gr < M) {
                const float4 v = *reinterpret_cast<float4*>(&as[r][c4 << 2]);
                const float4 g = reinterpret_cast<const float4*>(gamma)[c4];
                const float4 b = reinterpret_cast<const float4*>(beta)[c4];
                const float mu = s_mu[r], rs = s_rs[r];
                float4 o;
                o.x = (v.x - mu) * rs * g.x + b.x;
                o.y = (v.y - mu) * rs * g.y + b.y;
                o.z = (v.z - mu) * rs * g.z + b.z;
                o.w = (v.w - mu) * rs * g.w + b.w;
                *reinterpret_cast<float4*>(out + (size_t)gr * D + (c4 << 2)) = o;
            }
        }
    }
}

// ---------------------------------------------------------------------------
// Fused FFN + residual + LN, in-place capable (row-disjoint blocks):
// out = LN(x + relu(x@W1 + b1) @ W2 + b2)
// block: 256 threads, 32 rows; hidden [32,256] lives in LDS only.
// Same unroll-1 register discipline as gemm128_kernel.
// ---------------------------------------------------------------------------
__global__ __launch_bounds__(256, 4) void ffn_ln_kernel(
    const float* __restrict__ X,
    const float* __restrict__ W1, const float* __restrict__ b1,
    const float* __restrict__ W2, const float* __restrict__ b2,
    const float* __restrict__ gamma, const float* __restrict__ beta,
    float* __restrict__ out, int M)
{
    __shared__ float xs[32][132];
    __shared__ float hs[32][260];
    __shared__ float s_mu[32], s_rs[32];

    const int tid = threadIdx.x;
    const int m0 = blockIdx.x * 32;

    // stage x (32x128)
    for (int i = tid; i < 1024; i += 256) {
        const int r = i >> 5, c4 = i & 31;
        const int gr = m0 + r;
        const float4 v = (gr < M)
            ? reinterpret_cast<const float4*>(X + (size_t)gr * D)[c4]
            : f4_zero();
        *reinterpret_cast<float4*>(&xs[r][c4 << 2]) = v;
    }
    __syncthreads();

    // phase 1: hidden = relu(x @ W1 + b1)   (32 x 256)
    {
        const int tx = tid & 63;   // cols tx*4 (256 cols)
        const int ty = tid >> 6;   // rows ty*8..+7
        float acc[8][4];
#pragma unroll
        for (int r = 0; r < 8; ++r) { acc[r][0] = 0.f; acc[r][1] = 0.f; acc[r][2] = 0.f; acc[r][3] = 0.f; }
        const float* W1p = W1 + (tx << 2);
#pragma unroll 1
        for (int k = 0; k < 128; k += 4) {
            const float4 wv0 = *reinterpret_cast<const float4*>(W1p);
            const float4 wv1 = *reinterpret_cast<const float4*>(W1p + 256);
            const float4 wv2 = *reinterpret_cast<const float4*>(W1p + 512);
            const float4 wv3 = *reinterpret_cast<const float4*>(W1p + 768);
            W1p += 1024;
#pragma unroll
            for (int r = 0; r < 8; ++r) {
                const float4 av = *reinterpret_cast<const float4*>(&xs[(ty << 3) + r][k]);
                acc[r][0] = fmaf(av.x, wv0.x, acc[r][0]);
                acc[r][1] = fmaf(av.x, wv0.y, acc[r][1]);
                acc[r][2] = fmaf(av.x, wv0.z, acc[r][2]);
                acc[r][3] = fmaf(av.x, wv0.w, acc[r][3]);
                acc[r][0] = fmaf(av.y, wv1.x, acc[r][0]);
                acc[r][1] = fmaf(av.y, wv1.y, acc[r][1]);
                acc[r][2] = fmaf(av.y, wv1.z, acc[r][2]);
                acc[r][3] = fmaf(av.y, wv1.w, acc[r][3]);
                acc[r][0] = fmaf(av.z, wv2.x, acc[r][0]);
                acc[r][1] = fmaf(av.z, wv2.y, acc[r][1]);
                acc[r][2] = fmaf(av.z, wv2.z, acc[r][2]);
                acc[r][3] = fmaf(av.z, wv2.w, acc[r][3]);
                acc[r][0] = fmaf(av.w, wv3.x, acc[r][0]);
                acc[r][1] = fmaf(av.w, wv3.y, acc[r][1]);
                acc[r][2] = fmaf(av.w, wv3.z, acc[r][2]);
                acc[r][3] = fmaf(av.w, wv3.w, acc[r][3]);
            }
        }
        const float4 bb = *reinterpret_cast<const float4*>(b1 + (tx << 2));
#pragma unroll
        for (int r = 0; r < 8; ++r) {
            float4 hv;
            hv.x = fmaxf(acc[r][0] + bb.x, 0.f);
            hv.y = fmaxf(acc[r][1] + bb.y, 0.f);
            hv.z = fmaxf(acc[r][2] + bb.z, 0.f);
            hv.w = fmaxf(acc[r][3] + bb.w, 0.f);
            *reinterpret_cast<float4*>(&hs[(ty << 3) + r][tx << 2]) = hv;
        }
    }
    __syncthreads();

    // phase 2: y = hidden @ W2 + b2 + x  -> overwrite xs (owner-only, no race)
    {
        const int tx = tid & 31;   // cols tx*4 (128 cols)
        const int ty = tid >> 5;   // rows ty*4..+3
        float acc[4][4];
#pragma unroll
        for (int r = 0; r < 4; ++r) { acc[r][0] = 0.f; acc[r][1] = 0.f; acc[r][2] = 0.f; acc[r][3] = 0.f; }
        const float* W2p = W2 + (tx << 2);
#pragma unroll 1
        for (int k = 0; k < 256; k += 4) {
            const float4 wv0 = *reinterpret_cast<const float4*>(W2p);
            const float4 wv1 = *reinterpret_cast<const float4*>(W2p + D);
            const float4 wv2 = *reinterpret_cast<const float4*>(W2p + 2 * D);
            const float4 wv3 = *reinterpret_cast<const float4*>(W2p + 3 * D);
            W2p += 4 * D;
#pragma unroll
            for (int r = 0; r < 4; ++r) {
                const float4 av = *reinterpret_cast<const float4*>(&hs[(ty << 2) + r][k]);
                acc[r][0] = fmaf(av.x, wv0.x, acc[r][0]);
                acc[r][1] = fmaf(av.x, wv0.y, acc[r][1]);
                acc[r][2] = fmaf(av.x, wv0.z, acc[r][2]);
                acc[r][3] = fmaf(av.x, wv0.w, acc[r][3]);
                acc[r][0] = fmaf(av.y, wv1.x, acc[r][0]);
                acc[r][1] = fmaf(av.y, wv1.y, acc[r][1]);
                acc[r][2] = fmaf(av.y, wv1.z, acc[r][2]);
                acc[r][3] = fmaf(av.y, wv1.w, acc[r][3]);
                acc[r][0] = fmaf(av.z, wv2.x, acc[r][0]);
                acc[r][1] = fmaf(av.z, wv2.y, acc[r][1]);
                acc[r][2] = fmaf(av.z, wv2.z, acc[r][2]);
                acc[r][3] = fmaf(av.z, wv2.w, acc[r][3]);
                acc[r][0] = fmaf(av.w, wv3.x, acc[r][0]);
                acc[r][1] = fmaf(av.w, wv3.y, acc[r][1]);
                acc[r][2] = fmaf(av.w, wv3.z, acc[r][2]);
                acc[r][3] = fmaf(av.w, wv3.w, acc[r][3]);
            }
        }
        const float4 bb = *reinterpret_cast<const float4*>(b2 + (tx << 2));
#pragma unroll
        for (int r = 0; r < 4; ++r) {
            const int lr = (ty << 2) + r;
            float4 y = *reinterpret_cast<float4*>(&xs[lr][tx << 2]);  // residual
            y.x += acc[r][0] + bb.x;
            y.y += acc[r][1] + bb.y;
            y.z += acc[r][2] + bb.z;
            y.w += acc[r][3] + bb.w;
            *reinterpret_cast<float4*>(&xs[lr][tx << 2]) = y;
        }
    }
    __syncthreads();

    // LN: 8 threads per row, 16 cols each
    {
        const int row = tid >> 3, part = tid & 7;
        float s = 0.f, q = 0.f;
        const int c0 = part << 4;
#pragma unroll
        for (int c = 0; c < 16; ++c) { const float v = xs[row][c0 + c]; s += v; q = fmaf(v, v, q); }
        s += __shfl_xor(s, 1); q += __shfl_xor(q, 1);
        s += __shfl_xor(s, 2); q += __shfl_xor(q, 2);
        s += __shfl_xor(s, 4); q += __shfl_xor(q, 4);
        if (part == 0) {
            const float mu = s * (1.f / 128.f);
            const float var = q * (1.f / 128.f) - mu * mu;
            s_mu[row] = mu;
            s_rs[row] = rsqrtf(var + 1e-5f);
        }
    }
    __syncthreads();

    for (int i = tid; i < 1024; i += 256) {
        const int r = i >> 5, c4 = i & 31;
        const int gr = m0 + r;
        if (gr < M) {
            const float4 v = *reinterpret_cast<float4*>(&xs[r][c4 << 2]);
            const float4 g = reinterpret_cast<const float4*>(gamma)[c4];
            const float4 b = reinterpret_cast<const float4*>(beta)[c4];
            const float mu = s_mu[r], rs = s_rs[r];
            float4 o;
            o.x = (v.x - mu) * rs * g.x + b.x;
            o.y = (v.y - mu) * rs * g.y + b.y;
            o.z = (v.z - mu) * rs * g.z + b.z;
            o.w = (v.w - mu) * rs * g.w + b.w;
            *reinterpret_cast<float4*>(out + (size_t)gr * D + (c4 << 2)) = o;
        }
    }
}

// ---------------------------------------------------------------------------
// Edge kernel: one edge per 32-lane group (8 edges / 256-thread block).
//   score[h] = dot(K[src],Q[dst])/4 ; e1 = score*pe (in-place over pe);
//   sc[h] = exp(clip(sum_dh e1, -5, 5));
//   atomic scatter: wV[dst] += V[src]*sc ; z[dst,h] += sc
// ---------------------------------------------------------------------------
__global__ __launch_bounds__(256) void edge_kernel(
    const float* __restrict__ Q, const float* __restrict__ K, const float* __restrict__ V,
    const int* __restrict__ src, const int* __restrict__ dst,
    float* __restrict__ pe_e1, float* __restrict__ wV, float* __restrict__ z, int E)
{
    const int tid = threadIdx.x;
    const int slot = tid >> 5, l = tid & 31;
    const long long e = (long long)blockIdx.x * 8 + slot;
    if (e >= E) return;

    const int s = src[e], d = dst[e];
    const int head = l >> 2;

    const float4 kv = reinterpret_cast<const float4*>(K + (size_t)s * D)[l];
    const float4 qv = reinterpret_cast<const float4*>(Q + (size_t)d * D)[l];
    float dot = kv.x * qv.x + kv.y * qv.y + kv.z * qv.z + kv.w * qv.w;
    dot += __shfl_xor(dot, 1);
    dot += __shfl_xor(dot, 2);
    const float score = dot * 0.25f;  // 1/sqrt(16)

    const float4 pe4 = reinterpret_cast<const float4*>(pe_e1 + (size_t)e * D)[l];
    float4 e1;
    e1.x = score * pe4.x; e1.y = score * pe4.y; e1.z = score * pe4.z; e1.w = score * pe4.w;
    reinterpret_cast<float4*>(pe_e1 + (size_t)e * D)[l] = e1;

    float ss = e1.x + e1.y + e1.z + e1.w;
    ss += __shfl_xor(ss, 1);
    ss += __shfl_xor(ss, 2);
    const float sc = expf(fminf(fmaxf(ss, -5.f), 5.f));

    const float4 vv = reinterpret_cast<const float4*>(V + (size_t)s * D)[l];
    float* wrow = wV + (size_t)d * D + (l << 2);
    atomicAdd(wrow + 0, vv.x * sc);
    atomicAdd(wrow + 1, vv.y * sc);
    atomicAdd(wrow + 2, vv.z * sc);
    atomicAdd(wrow + 3, vv.w * sc);
    if ((l & 3) == 0) atomicAdd(z + (size_t)d * H + head, sc);
}

// ---------------------------------------------------------------------------
extern "C" void kernel_launch(void* const* d_in, const int* in_sizes, int n_in,
                              void* d_out, int out_size, void* d_ws, size_t ws_size,
                              hipStream_t stream)
{
    const float* h    = (const float*)d_in[0];
    const float* e    = (const float*)d_in[1];
    const int*   src  = (const int*)d_in[2];
    const int*   dst  = (const int*)d_in[3];
    const float* Wq   = (const float*)d_in[4];
    const float* Wk   = (const float*)d_in[5];
    const float* Wv   = (const float*)d_in[6];
    const float* Wpe  = (const float*)d_in[7];
    const float* Oh_w = (const float*)d_in[8];
    const float* Oh_b = (const float*)d_in[9];
    const float* Oe_w = (const float*)d_in[10];
    const float* Oe_b = (const float*)d_in[11];
    const float* g1h  = (const float*)d_in[12];
    const float* b1h  = (const float*)d_in[13];
    const float* g1e  = (const float*)d_in[14];
    const float* b1e  = (const float*)d_in[15];
    const float* F1h_w = (const float*)d_in[16];
    const float* F1h_b = (const float*)d_in[17];
    const float* F2h_w = (const float*)d_in[18];
    const float* F2h_b = (const float*)d_in[19];
    const float* F1e_w = (const float*)d_in[20];
    const float* F1e_b = (const float*)d_in[21];
    const float* F2e_w = (const float*)d_in[22];
    const float* F2e_b = (const float*)d_in[23];
    const float* g2h  = (const float*)d_in[24];
    const float* b2h  = (const float*)d_in[25];
    const float* g2e  = (const float*)d_in[26];
    const float* b2e  = (const float*)d_in[27];

    const int N = in_sizes[0] / D;
    const int E = in_sizes[1] / D;

    // workspace layout (floats): Q | K | V | wV | z      (~104 MB for N=50k)
    // pe/e1 (E*D = 409.6 MB) lives in d_out's ee region — written fully by the
    // pe GEMM before anything reads it; all later consumers are row-in-place safe.
    float* ws   = (float*)d_ws;
    float* Qb   = ws;
    float* Kb   = Qb + (size_t)N * D;
    float* Vb   = Kb + (size_t)N * D;
    float* wVb  = Vb + (size_t)N * D;
    float* zb   = wVb + (size_t)N * D;

    float* hh = (float*)d_out;                    // N*D
    float* ee = (float*)d_out + (size_t)N * D;    // E*D
    float* peb = ee;                              // pe -> e1 -> ee (in place)

    // zero the scatter accumulators (wV and z are adjacent)
    hipMemsetAsync(wVb, 0, ((size_t)N * D + (size_t)N * H) * sizeof(float), stream);

    const dim3 blk(256);
    const int gn = (N + 63) / 64;
    const int ge = (E + 63) / 64;

    gemm128_kernel<0, 0><<<gn, blk, 0, stream>>>(h, Wq, nullptr, nullptr, nullptr, nullptr, nullptr, Qb, N);
    gemm128_kernel<0, 0><<<gn, blk, 0, stream>>>(h, Wk, nullptr, nullptr, nullptr, nullptr, nullptr, Kb, N);
    gemm128_kernel<0, 0><<<gn, blk, 0, stream>>>(h, Wv, nullptr, nullptr, nullptr, nullptr, nullptr, Vb, N);
    gemm128_kernel<0, 0><<<ge, blk, 0, stream>>>(e, Wpe, nullptr, nullptr, nullptr, nullptr, nullptr, peb, E);

    edge_kernel<<<(E + 7) / 8, blk, 0, stream>>>(Qb, Kb, Vb, src, dst, peb, wVb, zb, E);

    // hh1 = LN(h + (wV/z)@Oh_w + Oh_b)
    gemm128_kernel<1, 1><<<gn, blk, 0, stream>>>(wVb, Oh_w, Oh_b, h, g1h, b1h, zb, hh, N);
    // ee1 = LN(e + e1@Oe_w + Oe_b)   (A == out, row-in-place safe)
    gemm128_kernel<1, 0><<<ge, blk, 0, stream>>>(peb, Oe_w, Oe_b, e, g1e, b1e, nullptr, ee, E);

    // FFN + LN, in-place on d_out regions
    ffn_ln_kernel<<<(N + 31) / 32, blk, 0, stream>>>(hh, F1h_w, F1h_b, F2h_w, F2h_b, g2h, b2h, hh, N);
    ffn_ln_kernel<<<(E + 31) / 32, blk, 0, stream>>>(ee, F1e_w, F1e_b, F2e_w, F2e_b, g2e, b2e, ee, E);
}